// Round 8
// baseline (27.060 us; speedup 1.0000x reference)
//
#include <hip/hip_runtime.h>
#include <math.h>

// ConfidenceBCELoss — flat 4096-elem segments (perfect balance, straight-line
// fast path) + product-accumulated log term + tiny combine kernel.
//   idx_b = last-nonzero index; kept region j < idx_b
//   num_b = sum_{j<idx} bce(x_j,t)*sig(j-5);  den_b = sum_{j<idx} sig(j-5)
//   out   = mean_b(num_b/den_b)
// Block (b,s) covers [s*4096,(s+1)*4096) ∩ [0,L4). Accumulates
//   Alin = sum (max(x,0) - x*t)
//   Alog = sum log2(1+exp(-|x|))  computed as log2(prod(1+e)) per 16 elems
//          (each thread's 16 factors in (1,2] -> P <= 2^16, exact enough; one
//          v_log2 per 16 elems instead of 16).
// sig==1.0f exactly in fp32 for j>=22 -> weights reduce to a 22-lane head
// correction (seg-0 block, from LDS-cached head). Boundary seg (the one
// containing L4) masks at float4 granularity and tracks (idx, mval).
// Partials are plain overwrites; combine kernel (1 block) finishes in fixed
// order. No atomics/fences — R3/R6 showed device-scope sync costs 20-200us.

#define LN2F 0.69314718055994531f

__device__ __forceinline__ float bce_nat(float x, float t) {
    const float e = __expf(-fabsf(x));
    return fmaf(-x, t, fmaxf(x, 0.0f) + __logf(1.0f + e));
}

__global__ __launch_bounds__(256) void seg_kernel(
    const float* __restrict__ x, const int* __restrict__ lengths,
    const float* __restrict__ target, float4* __restrict__ pseg,
    float2* __restrict__ phead, int S)
{
    const int bid = blockIdx.x;
    const int b = bid >> 2;
    const int s = bid & 3;
    const int tid = threadIdx.x;

    const int len = min(max(lengths[b], 1), S);
    const int L4  = (len + 3) & ~3;          // mult of 4, in [4096, 16384]
    const int lo  = s << 12;                 // segment start
    if (lo >= L4) return;                    // inactive segment

    const int s_last = (L4 - 1) >> 12;
    const bool boundary = (s == s_last);
    const float* row = x + (size_t)b * (size_t)S;
    const float t = target[b];

    __shared__ float s_head[24];
    __shared__ float sLin[4], sLog[4], sV[4];
    __shared__ int   sI[4];

    if (s == 0 && tid < 6)
        *reinterpret_cast<float4*>(&s_head[tid * 4]) =
            *reinterpret_cast<const float4*>(row + tid * 4);

    // 4 independent accumulator sets for ILP
    float P0 = 1.0f, P1 = 1.0f, P2 = 1.0f, P3 = 1.0f;
    float A0 = 0.0f, A1 = 0.0f, A2 = 0.0f, A3 = 0.0f;
    int maxidx = -1; float mval = 0.0f;

    const int j0 = lo + tid * 4;

#define GRP(vv, jj, PP, AA) do {                                   \
    const float g_[4] = {vv.x, vv.y, vv.z, vv.w};                  \
    _Pragma("unroll")                                              \
    for (int k_ = 0; k_ < 4; ++k_) {                               \
        const float xv_ = g_[k_];                                  \
        PP *= 1.0f + __expf(-fabsf(xv_));                          \
        AA += fmaf(-xv_, t, fmaxf(xv_, 0.0f));                     \
    } } while (0)

#define GRPI(vv, jj, PP, AA) do {                                  \
    const float g_[4] = {vv.x, vv.y, vv.z, vv.w};                  \
    _Pragma("unroll")                                              \
    for (int k_ = 0; k_ < 4; ++k_) {                               \
        const float xv_ = g_[k_];                                  \
        PP *= 1.0f + __expf(-fabsf(xv_));                          \
        AA += fmaf(-xv_, t, fmaxf(xv_, 0.0f));                     \
        if (xv_ != 0.0f) { maxidx = (jj) + k_; mval = xv_; }       \
    } } while (0)

    if (!boundary) {
        // straight-line: exactly 4096 elems, no bounds checks
        const float4 v0 = *reinterpret_cast<const float4*>(row + j0);
        const float4 v1 = *reinterpret_cast<const float4*>(row + j0 + 1024);
        const float4 v2 = *reinterpret_cast<const float4*>(row + j0 + 2048);
        const float4 v3 = *reinterpret_cast<const float4*>(row + j0 + 3072);
        GRP(v0, j0,        P0, A0);
        GRP(v1, j0 + 1024, P1, A1);
        GRP(v2, j0 + 2048, P2, A2);
        GRP(v3, j0 + 3072, P3, A3);
    } else {
        if (j0 < L4) {
            const float4 v = *reinterpret_cast<const float4*>(row + j0);
            GRPI(v, j0, P0, A0);
        }
        if (j0 + 1024 < L4) {
            const float4 v = *reinterpret_cast<const float4*>(row + j0 + 1024);
            GRPI(v, j0 + 1024, P1, A1);
        }
        if (j0 + 2048 < L4) {
            const float4 v = *reinterpret_cast<const float4*>(row + j0 + 2048);
            GRPI(v, j0 + 2048, P2, A2);
        }
        if (j0 + 3072 < L4) {
            const float4 v = *reinterpret_cast<const float4*>(row + j0 + 3072);
            GRPI(v, j0 + 3072, P3, A3);
        }
    }

    float Alin = (A0 + A1) + (A2 + A3);
    float Alog = __log2f(((P0 * P1) * (P2 * P3)));   // <= 2^16, exact enough

    // wave(64) reduce, then cross-wave via LDS
    #pragma unroll
    for (int off = 32; off > 0; off >>= 1) {
        Alin += __shfl_down(Alin, off);
        Alog += __shfl_down(Alog, off);
        const int   oi = __shfl_down(maxidx, off);
        const float ov = __shfl_down(mval, off);
        if (oi > maxidx) { maxidx = oi; mval = ov; }
    }
    const int wave = tid >> 6;
    if ((tid & 63) == 0) { sLin[wave] = Alin; sLog[wave] = Alog;
                           sI[wave] = maxidx; sV[wave] = mval; }
    __syncthreads();

    if (tid == 0) {
        #pragma unroll
        for (int w = 1; w < 4; ++w) {
            Alin += sLin[w]; Alog += sLog[w];
            if (sI[w] > maxidx) { maxidx = sI[w]; mval = sV[w]; }
        }
        if (boundary && maxidx < 0) { maxidx = L4 - 1; mval = 0.0f; }  // p=0 guard
        pseg[bid] = make_float4(Alin, Alog, __int_as_float(maxidx), mval);
    }

    // seg-0 block: head correction (idx >= 4095 > 22 always)
    if (s == 0) {
        __syncthreads();
        if (tid < 64) {
            float c = 0.0f, d = 0.0f;
            if (tid < 22) {
                const float sg = 1.0f / (1.0f + __expf(5.0f - (float)tid));
                c = bce_nat(s_head[tid], t) * (sg - 1.0f);
                d = sg;
            }
            #pragma unroll
            for (int off = 32; off > 0; off >>= 1) {
                c += __shfl_down(c, off);
                d += __shfl_down(d, off);
            }
            if (tid == 0) phead[b] = make_float2(c, d);
        }
    }
}

__global__ __launch_bounds__(1024) void combine_kernel(
    const float4* __restrict__ pseg, const float2* __restrict__ phead,
    const int* __restrict__ lengths, const float* __restrict__ target,
    float* __restrict__ out, int S, int B)
{
    const int tid = threadIdx.x;
    float acc = 0.0f;
    for (int r = tid; r < B; r += 1024) {
        const int len = min(max(lengths[r], 1), S);
        const int L4  = (len + 3) & ~3;
        const int s_last = (L4 - 1) >> 12;
        float Alin = 0.0f, Alog = 0.0f;
        float4 q;
        for (int s = 0; s <= s_last; ++s) {
            q = pseg[(r << 2) + s];
            Alin += q.x; Alog += q.y;
        }
        const int   idx  = __float_as_int(q.z);   // from boundary seg
        const float mval = q.w;
        const float t    = target[r];
        const float2 hd  = phead[r];
        const float e_m  = __expf(-fabsf(mval));
        Alog -= __log2f(1.0f + e_m) + (float)(L4 - 1 - idx);
        Alin -= fmaf(-mval, t, fmaxf(mval, 0.0f));
        const float den = hd.y + (float)(idx - 22);
        acc += (Alin + hd.x + LN2F * Alog) / den;
    }
    #pragma unroll
    for (int off = 32; off > 0; off >>= 1) acc += __shfl_down(acc, off);
    __shared__ float sw[16];
    if ((tid & 63) == 0) sw[tid >> 6] = acc;
    __syncthreads();
    if (tid == 0) {
        float tot = 0.0f;
        #pragma unroll
        for (int w = 0; w < 16; ++w) tot += sw[w];
        out[0] = tot / (float)B;
    }
}

extern "C" void kernel_launch(void* const* d_in, const int* in_sizes, int n_in,
                              void* d_out, int out_size, void* d_ws, size_t ws_size,
                              hipStream_t stream) {
    const float* logits  = (const float*)d_in[0];  // [B,S,1] fp32, zero-padded
    const int*   lengths = (const int*)d_in[1];    // [B] int32
    const float* target  = (const float*)d_in[2];  // [B,1] fp32
    float* out = (float*)d_out;

    const int B = in_sizes[2];          // 2048
    const int S = in_sizes[0] / B;      // 16384
    const int NSEG = S >> 12;           // 4096-elem segments (S mult of 4096)

    float4* pseg  = (float4*)d_ws;                       // B*NSEG float4
    float2* phead = (float2*)(pseg + (size_t)B * NSEG);  // B float2

    seg_kernel<<<B * NSEG, 256, 0, stream>>>(logits, lengths, target,
                                             pseg, phead, S);
    combine_kernel<<<1, 1024, 0, stream>>>(pseg, phead, lengths, target,
                                           out, S, B);
}

// Round 9
// 23.254 us; speedup vs baseline: 1.1637x; 1.1637x over previous
//
#include <hip/hip_runtime.h>
#include <math.h>

// ConfidenceBCELoss — half-row split + self-finishing partials + minimal combine.
//   idx_b = last-nonzero index; kept region j < idx_b
//   num_b = sum_{j<idx} bce(x_j,t)*sig(j-5);  den_b = sum_{j<idx} sig(j-5)
//   out   = mean_b(num_b/den_b)
// Row b -> TWO blocks: A=[0,H), B=[H,L4), H ~ L4/2 (mult of 4, >= 2048).
// Hot loop accumulates Alin = sum(max(x,0)-x*t), Alog = sum log2(1+exp(-|x|)).
// sig(j-5)==1.0f exactly in fp32 for j>=22 -> block A folds the 22-lane head
// correction (c22,d22). Block B owns idx=last-nonzero (idx=len-1 >= H always)
// and folds the FULL tail correction + den partial (idx-22) into its payload.
// Per row the combine then needs only: pA=(linA+c22, logA, d22, 0) and
// pB=(linB-corr, logB-corr, idx-22, 0):
//   result = (pA.x+pB.x + LN2*(pA.y+pB.y)) / (pA.z+pB.z)
// -> combine = 2 coalesced float4 loads + ~6 flops per row, one latency trip.
// No atomics/fences (R3/R6: device-scope sync costs 20-200us).
// Per-block work kept >= 2048 elems (R8: smaller blocks lose to fixed cost).

#define LN2F 0.69314718055994531f

__device__ __forceinline__ float bce_nat(float x, float t) {
    const float e = __expf(-fabsf(x));
    return fmaf(-x, t, fmaxf(x, 0.0f) + __logf(1.0f + e));
}

#define ACC(xv) do {                                   \
    const float e_ = __expf(-fabsf(xv));               \
    Alog += __log2f(1.0f + e_);                        \
    Alin += fmaf(-(xv), t, fmaxf((xv), 0.0f)); } while (0)

__global__ __launch_bounds__(256) void half_row_kernel(
    const float* __restrict__ x, const int* __restrict__ lengths,
    const float* __restrict__ target, float4* __restrict__ pA,
    float4* __restrict__ pB, int S)
{
    const int bid = blockIdx.x;
    const int b = bid >> 1;
    const bool isB = (bid & 1) != 0;
    const float* row = x + (size_t)b * (size_t)S;
    const float t = target[b];
    const int tid = threadIdx.x;
    const int len = min(max(lengths[b], 1), S);
    const int L4 = (len + 3) & ~3;         // mult of 4, <= S
    const int H  = (L4 >> 3) << 2;         // mult of 4, ~L4/2, >= 2048
    const int lo = isB ? H : 0;
    const int hi = isB ? L4 : H;
    const int n  = hi - lo;                // >= 2048
    const int lastb = lo + (((n - 1) >> 12) << 12);   // final masked 4096-chunk

    __shared__ float s_head[24];
    __shared__ float sLin[4], sLog[4], sV[4];
    __shared__ int   sI[4];
    __shared__ float s_lin, s_log;

    if (!isB && tid < 6)
        *reinterpret_cast<float4*>(&s_head[tid * 4]) =
            *reinterpret_cast<const float4*>(row + tid * 4);

    float Alin = 0.0f, Alog = 0.0f;
    int maxidx = -1; float mval = 0.0f;

    // fast phase: full 4096-chunks, 4 outstanding dwordx4, no bounds checks
    for (int base = lo; base < lastb; base += 4096) {
        const int j0 = base + tid * 4;
        const float4 v0 = *reinterpret_cast<const float4*>(row + j0);
        const float4 v1 = *reinterpret_cast<const float4*>(row + j0 + 1024);
        const float4 v2 = *reinterpret_cast<const float4*>(row + j0 + 2048);
        const float4 v3 = *reinterpret_cast<const float4*>(row + j0 + 3072);
        const float vs[16] = {v0.x, v0.y, v0.z, v0.w, v1.x, v1.y, v1.z, v1.w,
                              v2.x, v2.y, v2.z, v2.w, v3.x, v3.y, v3.z, v3.w};
        #pragma unroll
        for (int k = 0; k < 16; ++k) { const float xv = vs[k]; ACC(xv); }
    }

    // final chunk [lastb, hi): masked at float4 granularity
    if (isB) {
        #pragma unroll
        for (int seg = 0; seg < 4; ++seg) {
            const int j0 = lastb + (seg << 10) + tid * 4;
            if (j0 < hi) {
                const float4 v = *reinterpret_cast<const float4*>(row + j0);
                const float vs[4] = {v.x, v.y, v.z, v.w};
                #pragma unroll
                for (int k = 0; k < 4; ++k) {
                    const float xv = vs[k]; ACC(xv);
                    if (xv != 0.0f) { maxidx = j0 + k; mval = xv; }
                }
            }
        }
    } else {
        #pragma unroll
        for (int seg = 0; seg < 4; ++seg) {
            const int j0 = lastb + (seg << 10) + tid * 4;
            if (j0 < hi) {
                const float4 v = *reinterpret_cast<const float4*>(row + j0);
                const float vs[4] = {v.x, v.y, v.z, v.w};
                #pragma unroll
                for (int k = 0; k < 4; ++k) { const float xv = vs[k]; ACC(xv); }
            }
        }
    }

    // wave(64) reduce, then cross-wave via LDS
    #pragma unroll
    for (int off = 32; off > 0; off >>= 1) {
        Alin += __shfl_down(Alin, off);
        Alog += __shfl_down(Alog, off);
        const int   oi = __shfl_down(maxidx, off);
        const float ov = __shfl_down(mval, off);
        if (oi > maxidx) { maxidx = oi; mval = ov; }
    }
    const int wave = tid >> 6;
    if ((tid & 63) == 0) { sLin[wave] = Alin; sLog[wave] = Alog;
                           sI[wave] = maxidx; sV[wave] = mval; }
    __syncthreads();

    if (isB) {
        if (tid == 0) {
            #pragma unroll
            for (int w = 1; w < 4; ++w) {
                Alin += sLin[w]; Alog += sLog[w];
                if (sI[w] > maxidx) { maxidx = sI[w]; mval = sV[w]; }
            }
            int idx; float mv;
            if (maxidx < 0) { idx = hi - 1; mv = 0.0f; }  // prob-0 guard
            else            { idx = maxidx; mv = mval; }
            // fold tail correction: remove elem idx and zero run (idx, L4)
            const float e_m  = __expf(-fabsf(mv));
            const float logC = Alog - __log2f(1.0f + e_m)
                               - (float)(L4 - 1 - idx);
            const float linC = Alin - fmaf(-mv, t, fmaxf(mv, 0.0f));
            pB[b] = make_float4(linC, logC, (float)(idx - 22), 0.0f);
        }
    } else {
        if (tid == 0) {
            #pragma unroll
            for (int w = 1; w < 4; ++w) { Alin += sLin[w]; Alog += sLog[w]; }
            s_lin = Alin; s_log = Alog;
        }
        __syncthreads();
        if (tid < 64) {      // wave 0: head correction (idx > 22 always)
            float c = 0.0f, d = 0.0f;
            if (tid < 22) {
                const float sg = 1.0f / (1.0f + __expf(5.0f - (float)tid));
                c = bce_nat(s_head[tid], t) * (sg - 1.0f);
                d = sg;
            }
            #pragma unroll
            for (int off = 32; off > 0; off >>= 1) {
                c += __shfl_down(c, off);
                d += __shfl_down(d, off);
            }
            if (tid == 0)
                pA[b] = make_float4(s_lin + c, s_log, d, 0.0f);
        }
    }
}

__device__ __forceinline__ float finish_row(float4 a, float4 bq) {
    return (a.x + bq.x + LN2F * (a.y + bq.y)) / (a.z + bq.z);
}

__global__ __launch_bounds__(1024) void combine_kernel(
    const float4* __restrict__ pA, const float4* __restrict__ pB,
    float* __restrict__ out, int B)
{
    const int tid = threadIdx.x;
    float s = 0.0f;
    // unroll x2: both rows' loads issue before either finish (1 latency trip)
    for (int r0 = tid; r0 < B; r0 += 2048) {
        const int r1 = r0 + 1024;
        const bool h1 = r1 < B;
        const float4 a0 = pA[r0], b0 = pB[r0];
        float4 a1, b1;
        if (h1) { a1 = pA[r1]; b1 = pB[r1]; }
        s += finish_row(a0, b0);
        if (h1) s += finish_row(a1, b1);
    }
    #pragma unroll
    for (int off = 32; off > 0; off >>= 1) s += __shfl_down(s, off);
    __shared__ float sw[16];
    if ((tid & 63) == 0) sw[tid >> 6] = s;
    __syncthreads();
    if (tid == 0) {
        float tot = 0.0f;
        #pragma unroll
        for (int w = 0; w < 16; ++w) tot += sw[w];
        out[0] = tot / (float)B;
    }
}

extern "C" void kernel_launch(void* const* d_in, const int* in_sizes, int n_in,
                              void* d_out, int out_size, void* d_ws, size_t ws_size,
                              hipStream_t stream) {
    const float* logits  = (const float*)d_in[0];  // [B,S,1] fp32, zero-padded
    const int*   lengths = (const int*)d_in[1];    // [B] int32
    const float* target  = (const float*)d_in[2];  // [B,1] fp32
    float* out = (float*)d_out;

    const int B = in_sizes[2];          // 2048
    const int S = in_sizes[0] / B;      // 16384

    float4* pA = (float4*)d_ws;                    // B float4s (overwritten)
    float4* pB = pA + B;                           // B float4s (overwritten)

    half_row_kernel<<<2 * B, 256, 0, stream>>>(logits, lengths, target,
                                               pA, pB, S);
    combine_kernel<<<1, 1024, 0, stream>>>(pA, pB, out, B);
}

// Round 10
// 22.541 us; speedup vs baseline: 1.2005x; 1.0317x over previous
//
#include <hip/hip_runtime.h>
#include <math.h>

// ConfidenceBCELoss — half-row split, FLATTENED max-MLP scan + product-log.
//   idx_b = last-nonzero index; kept region j < idx_b
//   num_b = sum_{j<idx} bce(x_j,t)*sig(j-5);  den_b = sum_{j<idx} sig(j-5)
//   out   = mean_b(num_b/den_b)
// Row b -> TWO blocks: A=[0,H), B=[H,L4), H ~ L4/2 (mult of 4). n=hi-lo is in
// [2048, 8192] => at most 8 segments of 1024 elems. ALL segment loads are
// issued upfront (8 dwordx4 in flight per wave -> one latency trip per block),
// then one straight-line compute pass:
//   Alin += max(x,0) - x*t          (fma+fmax)
//   P    *= 1 + exp(-|x|)           (factors in (1,2]; <=2^16 per accumulator;
//                                    Alog = log2(P0*P1) ONCE per thread —
//                                    1 trans op/elem instead of 2; R8-validated)
// sig(j-5)==1.0f exactly in fp32 for j>=22 -> block A folds the 22-lane head
// correction; block B owns idx (idx=len-1>=H always) and folds the full tail
// correction + den partial. Combine: 2 float4 loads + ~6 flops per row.
// No atomics/fences (R3/R6: device-scope sync costs 20-200us). Per-block work
// >= 2048 elems (R8: smaller blocks lose to fixed cost).

#define LN2F 0.69314718055994531f

__device__ __forceinline__ float bce_nat(float x, float t) {
    const float e = __expf(-fabsf(x));
    return fmaf(-x, t, fmaxf(x, 0.0f) + __logf(1.0f + e));
}

__global__ __launch_bounds__(256) void half_row_kernel(
    const float* __restrict__ x, const int* __restrict__ lengths,
    const float* __restrict__ target, float4* __restrict__ pA,
    float4* __restrict__ pB, int S)
{
    const int bid = blockIdx.x;
    const int b = bid >> 1;
    const bool isB = (bid & 1) != 0;
    const float* row = x + (size_t)b * (size_t)S;
    const float t = target[b];
    const int tid = threadIdx.x;
    const int len = min(max(lengths[b], 1), S);
    const int L4 = (len + 3) & ~3;         // mult of 4, <= S
    const int H  = (L4 >> 3) << 2;         // mult of 4, ~L4/2, >= 2048
    const int lo = isB ? H : 0;
    const int hi = isB ? L4 : H;           // hi-lo in [2048, 8192]

    __shared__ float s_head[24];
    __shared__ float sLin[4], sLog[4], sV[4];
    __shared__ int   sI[4];
    __shared__ float s_lin, s_log;

    if (!isB && tid < 6)
        *reinterpret_cast<float4*>(&s_head[tid * 4]) =
            *reinterpret_cast<const float4*>(row + tid * 4);

    const int j0 = lo + tid * 4;

    // ---- issue ALL segment loads upfront (8 dwordx4 in flight) ----
    float4 v0, v1, v2, v3, v4, v5, v6, v7;
    const bool g0 = (j0          ) < hi;   // always true (hi-lo >= 2048)
    const bool g1 = (j0 + 1 * 1024) < hi;  // always true
    const bool g2 = (j0 + 2 * 1024) < hi;
    const bool g3 = (j0 + 3 * 1024) < hi;
    const bool g4 = (j0 + 4 * 1024) < hi;
    const bool g5 = (j0 + 5 * 1024) < hi;
    const bool g6 = (j0 + 6 * 1024) < hi;
    const bool g7 = (j0 + 7 * 1024) < hi;
    v0 = *reinterpret_cast<const float4*>(row + j0);
    v1 = *reinterpret_cast<const float4*>(row + j0 + 1 * 1024);
    if (g2) v2 = *reinterpret_cast<const float4*>(row + j0 + 2 * 1024);
    if (g3) v3 = *reinterpret_cast<const float4*>(row + j0 + 3 * 1024);
    if (g4) v4 = *reinterpret_cast<const float4*>(row + j0 + 4 * 1024);
    if (g5) v5 = *reinterpret_cast<const float4*>(row + j0 + 5 * 1024);
    if (g6) v6 = *reinterpret_cast<const float4*>(row + j0 + 6 * 1024);
    if (g7) v7 = *reinterpret_cast<const float4*>(row + j0 + 7 * 1024);

    // ---- straight-line compute pass ----
    float P0 = 1.0f, P1 = 1.0f;            // each <= 2^16 (16 factors in (1,2])
    float A0 = 0.0f, A1 = 0.0f;
    int maxidx = -1; float mval = 0.0f;    // used by B only; cheap to track

#define SEG(vv, gg, ss, PP, AA) do {                                   \
    if (gg) {                                                          \
        const float s_[4] = {vv.x, vv.y, vv.z, vv.w};                  \
        const int jb_ = j0 + (ss) * 1024;                              \
        _Pragma("unroll")                                              \
        for (int k_ = 0; k_ < 4; ++k_) {                               \
            const float xv_ = s_[k_];                                  \
            PP *= 1.0f + __expf(-fabsf(xv_));                          \
            AA += fmaf(-xv_, t, fmaxf(xv_, 0.0f));                     \
            if (xv_ != 0.0f) { maxidx = jb_ + k_; mval = xv_; }        \
        }                                                              \
    } } while (0)

    SEG(v0, g0, 0, P0, A0);
    SEG(v1, g1, 1, P1, A1);
    SEG(v2, g2, 2, P0, A0);
    SEG(v3, g3, 3, P1, A1);
    SEG(v4, g4, 4, P0, A0);
    SEG(v5, g5, 5, P1, A1);
    SEG(v6, g6, 6, P0, A0);
    SEG(v7, g7, 7, P1, A1);
#undef SEG

    float Alin = A0 + A1;
    float Alog = __log2f(P0 * P1);         // <= 2^32, exact enough (R8: absmax 0)

    // ---- wave(64) reduce, then cross-wave via LDS ----
    #pragma unroll
    for (int off = 32; off > 0; off >>= 1) {
        Alin += __shfl_down(Alin, off);
        Alog += __shfl_down(Alog, off);
        const int   oi = __shfl_down(maxidx, off);
        const float ov = __shfl_down(mval, off);
        if (oi > maxidx) { maxidx = oi; mval = ov; }
    }
    const int wave = tid >> 6;
    if ((tid & 63) == 0) { sLin[wave] = Alin; sLog[wave] = Alog;
                           sI[wave] = maxidx; sV[wave] = mval; }
    __syncthreads();

    if (isB) {
        if (tid == 0) {
            #pragma unroll
            for (int w = 1; w < 4; ++w) {
                Alin += sLin[w]; Alog += sLog[w];
                if (sI[w] > maxidx) { maxidx = sI[w]; mval = sV[w]; }
            }
            int idx; float mv;
            if (maxidx < 0) { idx = hi - 1; mv = 0.0f; }  // prob-0 guard
            else            { idx = maxidx; mv = mval; }
            // fold tail correction: remove elem idx and zero run (idx, L4)
            const float e_m  = __expf(-fabsf(mv));
            const float logC = Alog - __log2f(1.0f + e_m)
                               - (float)(L4 - 1 - idx);
            const float linC = Alin - fmaf(-mv, t, fmaxf(mv, 0.0f));
            pB[b] = make_float4(linC, logC, (float)(idx - 22), 0.0f);
        }
    } else {
        if (tid == 0) {
            #pragma unroll
            for (int w = 1; w < 4; ++w) { Alin += sLin[w]; Alog += sLog[w]; }
            s_lin = Alin; s_log = Alog;
        }
        __syncthreads();
        if (tid < 64) {      // wave 0: head correction (idx > 22 always)
            float c = 0.0f, d = 0.0f;
            if (tid < 22) {
                const float sg = 1.0f / (1.0f + __expf(5.0f - (float)tid));
                c = bce_nat(s_head[tid], t) * (sg - 1.0f);
                d = sg;
            }
            #pragma unroll
            for (int off = 32; off > 0; off >>= 1) {
                c += __shfl_down(c, off);
                d += __shfl_down(d, off);
            }
            if (tid == 0)
                pA[b] = make_float4(s_lin + c, s_log, d, 0.0f);
        }
    }
}

__device__ __forceinline__ float finish_row(float4 a, float4 bq) {
    return (a.x + bq.x + LN2F * (a.y + bq.y)) / (a.z + bq.z);
}

__global__ __launch_bounds__(1024) void combine_kernel(
    const float4* __restrict__ pA, const float4* __restrict__ pB,
    float* __restrict__ out, int B)
{
    const int tid = threadIdx.x;
    float s = 0.0f;
    // unroll x2: both rows' loads issue before either finish (1 latency trip)
    for (int r0 = tid; r0 < B; r0 += 2048) {
        const int r1 = r0 + 1024;
        const bool h1 = r1 < B;
        const float4 a0 = pA[r0], b0 = pB[r0];
        float4 a1, b1;
        if (h1) { a1 = pA[r1]; b1 = pB[r1]; }
        s += finish_row(a0, b0);
        if (h1) s += finish_row(a1, b1);
    }
    #pragma unroll
    for (int off = 32; off > 0; off >>= 1) s += __shfl_down(s, off);
    __shared__ float sw[16];
    if ((tid & 63) == 0) sw[tid >> 6] = s;
    __syncthreads();
    if (tid == 0) {
        float tot = 0.0f;
        #pragma unroll
        for (int w = 0; w < 16; ++w) tot += sw[w];
        out[0] = tot / (float)B;
    }
}

extern "C" void kernel_launch(void* const* d_in, const int* in_sizes, int n_in,
                              void* d_out, int out_size, void* d_ws, size_t ws_size,
                              hipStream_t stream) {
    const float* logits  = (const float*)d_in[0];  // [B,S,1] fp32, zero-padded
    const int*   lengths = (const int*)d_in[1];    // [B] int32
    const float* target  = (const float*)d_in[2];  // [B,1] fp32
    float* out = (float*)d_out;

    const int B = in_sizes[2];          // 2048
    const int S = in_sizes[0] / B;      // 16384

    float4* pA = (float4*)d_ws;                    // B float4s (overwritten)
    float4* pB = pA + B;                           // B float4s (overwritten)

    half_row_kernel<<<2 * B, 256, 0, stream>>>(logits, lengths, target,
                                               pA, pB, S);
    combine_kernel<<<1, 1024, 0, stream>>>(pA, pB, out, B);
}